// Round 17
// baseline (59.962 us; speedup 1.0000x reference)
//
#include <hip/hip_runtime.h>
#include <hip/hip_bf16.h>

#define B_   16
#define L_   256
#define D_   512
#define C_   8
#define P_   12
#define LOUT 244
#define O_   512
#define GM   3904   // 122 * 32 exactly
#define BM   32
#define BN   256
#define BK   32
#define NMT  122
#define NSTEP 16    // D_/BK

typedef __attribute__((ext_vector_type(8))) short bf16x8;
typedef __attribute__((ext_vector_type(4))) float f32x4;

__device__ __forceinline__ unsigned short f2bf(float f) {
    unsigned int u = __float_as_uint(f);
    unsigned int r = (u + 0x7FFFu + ((u >> 16) & 1u)) >> 16;
    return (unsigned short)r;
}

__device__ __forceinline__ void async_copy16(const void* g, void* l) {
    __builtin_amdgcn_global_load_lds(
        (const __attribute__((address_space(1))) unsigned int*)g,
        (__attribute__((address_space(3))) unsigned int*)l, 16, 0, 0);
}

// ---------------------------------------------------------------------------
// ws_convert: Ws f32 -> bf16 (one float4 per thread)
// ---------------------------------------------------------------------------
__global__ __launch_bounds__(256) void ws_convert(const float* __restrict__ Ws,
                                                  unsigned short* __restrict__ wsb) {
    int g = blockIdx.x * 256 + threadIdx.x;   // 524288 float4s
    float4 v = ((const float4*)Ws)[g];
    ushort4 o;
    o.x = f2bf(v.x); o.y = f2bf(v.y); o.z = f2bf(v.z); o.w = f2bf(v.w);
    ((ushort4*)wsb)[g] = o;
}

// ---------------------------------------------------------------------------
// fused v2: per (c,mt,nt): out[r,o] = FIR_c(inp)[r,:] . Ws_c[o,:] + bias.
//   NO tmp round-trip (kills 64 MB of HBM + the serial prep kernel).
//   BM=32 (122*32=GM exact), BN=256, BK=32, 512 thr = 8 waves, 1m x 8n
//   (wave tile 32x32, acc[2][2]).
//   A panel [32][512] bf16 (32 KB LDS): FIR prologue (r7-verified pattern:
//     8-row sliding window, batch-crossing rebase), swizzle chunk^(r&7)
//     on both ds_write and frag read -> 2-way (free).
//   B: r12-verified DMA path: 3 x 16 KB, global_load_lds x16, source
//     swizzle cc^(row&3), counted vmcnt(2) (0 at tail), one barrier/step.
//   LDS = 32 + 48 = 80 KB -> 2 blocks/CU (4 waves/SIMD TLP).
//   bid = mt*16 + nt*8 + c: channel per XCD (wsb L2-res), inp L3-shared.
// ---------------------------------------------------------------------------
__global__ __launch_bounds__(512, 4) void fused(const float* __restrict__ inp,
                                                const unsigned short* __restrict__ wsb,
                                                const float* __restrict__ bs,
                                                const float* __restrict__ Wt,
                                                const float* __restrict__ bt,
                                                float* __restrict__ out) {
    __shared__ unsigned short Al[BM * D_];      // 32 KB
    __shared__ unsigned short Bsh[3][BN * BK];  // 3 x 16 KB

    int bid = blockIdx.x;
    int c  = bid & 7;
    int nt = (bid >> 3) & 1;
    int mt = bid >> 4;                 // 0..121
    int row0 = mt * BM;
    int o0   = nt * BN;
    int tid = threadIdx.x, lane = tid & 63, wid = tid >> 6;   // wid = wn

    const unsigned short* Bb = wsb + ((size_t)c * O_ + o0) * D_;

    // FIR weights (wave-uniform -> SGPR)
    float w[P_];
#pragma unroll
    for (int p = 0; p < P_; ++p) w[p] = Wt[c * P_ + p];

    // per stage: B tile 1024 16B-chunks, 2 per thread (r12 verbatim)
#define STAGE(bi, kb)                                                         \
    _Pragma("unroll")                                                         \
    for (int h = 0; h < 2; ++h) {                                             \
        int q = h * 512 + tid;                                                \
        int row = q >> 2, cc = q & 3;                                         \
        int sc = cc ^ (row & 3);                                              \
        async_copy16(Bb + (size_t)row * D_ + (kb) + sc * 8,                   \
                     (unsigned short*)Bsh[bi] + q * 8);                       \
    }

    // ---- issue first two B stages; DMA rides under the FIR burst ----
    STAGE(0, 0)
    STAGE(1, BK)

    // ---- FIR prologue -> A panel (r7-verified sliding-window pattern) ----
    {
        int rgrp = tid >> 7;            // 0..3 -> local rows rgrp*8..+7
        int dq   = tid & 127;           // d-quad
        int gr0 = row0 + rgrp * 8;
        int fb = gr0 / LOUT, fl = gr0 % LOUT;
        int cross = LOUT - fl;          // j == cross -> new batch (if < 8)
        int fb2 = (cross < 8) ? fb + 1 : fb;
        const float* base  = inp + ((size_t)fb * L_ + fl) * D_ + dq * 4;
        const float* base2 = inp + ((size_t)fb2 * L_) * D_ + dq * 4;

        float4 win[P_];
        const float* cur = base;
        int off = 0;
#pragma unroll
        for (int j = 0; j < 8; ++j) {
            if (j == 0 || j == cross) {
                const float* bp = (j == 0) ? base : base2;
                cur = bp; off = 0;
#pragma unroll
                for (int k = 0; k < P_; ++k)
                    win[k] = *(const float4*)(bp + (size_t)k * D_);
            } else {
#pragma unroll
                for (int k = 0; k < P_ - 1; ++k) win[k] = win[k + 1];
                win[P_ - 1] = *(const float4*)(cur + (size_t)(off + P_) * D_);
                ++off;
            }
            float sx = 0.f, sy = 0.f, sz = 0.f, sw = 0.f;
#pragma unroll
            for (int p = 0; p < P_; ++p) {
                sx += w[p] * win[p].x;
                sy += w[p] * win[p].y;
                sz += w[p] * win[p].z;
                sw += w[p] * win[p].w;
            }
            int r = rgrp * 8 + j;
            // swizzle: 16B chunk (dq>>1) ^ (r&7); 8B half dq&1
            int idx = r * D_ + ((((dq >> 1) ^ (r & 7)) << 3) + ((dq & 1) << 2));
            ushort4 ov;
            ov.x = f2bf(sx); ov.y = f2bf(sy);
            ov.z = f2bf(sz); ov.w = f2bf(sw);
            *(ushort4*)&Al[idx] = ov;
        }
    }

    // drain: B stages 0,1 certified (provable), FIR ds_writes visible
    asm volatile("s_waitcnt vmcnt(0) lgkmcnt(0)" ::: "memory");
    __builtin_amdgcn_sched_barrier(0);
    asm volatile("s_barrier" ::: "memory");

    f32x4 acc[2][2];
#pragma unroll
    for (int m = 0; m < 2; ++m)
#pragma unroll
        for (int n = 0; n < 2; ++n)
            acc[m][n] = (f32x4){0.f, 0.f, 0.f, 0.f};

    // one K=32 slice: A from static panel (k-chunks t*4..t*4+3), B from ring
#define MFMA_STEP(t, bi)                                                      \
    {                                                                         \
        bf16x8 af[2], bq[2];                                                  \
        _Pragma("unroll")                                                     \
        for (int m = 0; m < 2; ++m) {                                         \
            int r = m * 16 + (lane & 15);                                     \
            int c0 = (t) * 4 + (lane >> 4);                                   \
            af[m] = *(const bf16x8*)&Al[r * D_ + ((c0 ^ (r & 7)) << 3)];      \
        }                                                                     \
        _Pragma("unroll")                                                     \
        for (int n = 0; n < 2; ++n) {                                         \
            int o = wid * 32 + n * 16 + (lane & 15);                          \
            bq[n] = *(const bf16x8*)&Bsh[bi][o * BK +                         \
                    (((lane >> 4) ^ (o & 3)) << 3)];                          \
        }                                                                     \
        _Pragma("unroll")                                                     \
        for (int m = 0; m < 2; ++m)                                           \
            _Pragma("unroll")                                                 \
            for (int n = 0; n < 2; ++n)                                       \
                acc[m][n] = __builtin_amdgcn_mfma_f32_16x16x32_bf16(          \
                    af[m], bq[n], acc[m][n], 0, 0, 0);                        \
    }

    // ---- K-loop: 16 steps, 3-buffer B, counted vmcnt (r12 scheme) ----
#pragma unroll
    for (int t = 0; t < NSTEP; ++t) {
        MFMA_STEP(t, t % 3)
        if (t == NSTEP - 1) break;
        asm volatile("s_waitcnt lgkmcnt(0)" ::: "memory");
        __builtin_amdgcn_sched_barrier(0);
        if (t + 2 < NSTEP) STAGE((t + 2) % 3, (t + 2) * BK)
        if (t < NSTEP - 2)
            asm volatile("s_waitcnt vmcnt(2)" ::: "memory");  // certify t+1
        else
            asm volatile("s_waitcnt vmcnt(0)" ::: "memory");  // tail
        __builtin_amdgcn_sched_barrier(0);
        asm volatile("s_barrier" ::: "memory");
    }

    // ---- bias + store ----
    float S = 0.f;
#pragma unroll
    for (int p = 0; p < P_; ++p) S += w[p];
    float btc = bt[c];

#pragma unroll
    for (int m = 0; m < 2; ++m) {
        int rb = row0 + m * 16 + ((lane >> 4) << 2);
#pragma unroll
        for (int n = 0; n < 2; ++n) {
            int col = o0 + wid * 32 + n * 16 + (lane & 15);
            float add = bs[c * O_ + col] * S + btc;
#pragma unroll
            for (int i = 0; i < 4; ++i)
                out[((size_t)(rb + i) * C_ + c) * O_ + col] = acc[m][n][i] + add;
        }
    }
#undef STAGE
#undef MFMA_STEP
}

// ---------------------------------------------------------------------------
// Fallback (ws too small): slow but correct, no workspace.
// ---------------------------------------------------------------------------
__global__ __launch_bounds__(256) void naive_k(const float* __restrict__ inp,
                                               const float* __restrict__ Ws,
                                               const float* __restrict__ bs,
                                               const float* __restrict__ Wt,
                                               const float* __restrict__ bt,
                                               float* __restrict__ out) {
    __shared__ float tmp[D_];
    int bid = blockIdx.x;
    int c = bid & 7; int r = bid >> 3;
    int l = r % LOUT; int b = r / LOUT;
    int tid = threadIdx.x;

    for (int d = tid; d < D_; d += 256) {
        float s = 0.f;
        for (int p = 0; p < P_; ++p)
            s += Wt[c * P_ + p] * inp[((size_t)b * L_ + l + p) * D_ + d];
        tmp[d] = s;
    }
    __syncthreads();
    float S = 0.f;
    for (int p = 0; p < P_; ++p) S += Wt[c * P_ + p];
    for (int o = tid; o < O_; o += 256) {
        const float* wrow = Ws + ((size_t)c * O_ + o) * D_;
        float s = 0.f;
        for (int d = 0; d < D_; ++d) s += wrow[d] * tmp[d];
        out[(((size_t)b * LOUT + l) * C_ + c) * O_ + o] =
            s + bs[c * O_ + o] * S + bt[c];
    }
}

extern "C" void kernel_launch(void* const* d_in, const int* in_sizes, int n_in,
                              void* d_out, int out_size, void* d_ws, size_t ws_size,
                              hipStream_t stream) {
    const float* inp = (const float*)d_in[0];
    const float* Ws  = (const float*)d_in[1];
    const float* bs  = (const float*)d_in[2];
    const float* Wt  = (const float*)d_in[3];
    const float* bt  = (const float*)d_in[4];
    float* out = (float*)d_out;

    const size_t WSBB = (size_t)C_ * O_ * D_ * 2;   // 4,194,304 bytes

    if (ws_size >= WSBB) {
        unsigned short* wsb = (unsigned short*)d_ws;
        ws_convert<<<2048, 256, 0, stream>>>(Ws, wsb);
        fused<<<NMT * 2 * C_, 512, 0, stream>>>(inp, wsb, bs, Wt, bt, out);
    } else {
        naive_k<<<B_ * LOUT * C_, 256, 0, stream>>>(inp, Ws, bs, Wt, bt, out);
    }
}

// Round 18
// 41.260 us; speedup vs baseline: 1.4533x; 1.4533x over previous
//
#include <hip/hip_runtime.h>
#include <hip/hip_bf16.h>

#define B_   16
#define L_   256
#define D_   512
#define C_   8
#define P_   12
#define LOUT 244
#define O_   512
#define GM   3904   // 16*244 rows per channel
#define BM   256
#define BN   256
#define BK   32
#define NMT  16     // ceil(3904/256)
#define NNT  2
#define NSTEP 16    // D_/BK
#define NFIRB 488   // r15 prep v3: 2 tasks per block

typedef __attribute__((ext_vector_type(8))) short bf16x8;
typedef __attribute__((ext_vector_type(4))) float f32x4;

__device__ __forceinline__ unsigned short f2bf(float f) {
    unsigned int u = __float_as_uint(f);
    unsigned int r = (u + 0x7FFFu + ((u >> 16) & 1u)) >> 16;
    return (unsigned short)r;
}

__device__ __forceinline__ void async_copy16(const void* g, void* l) {
    __builtin_amdgcn_global_load_lds(
        (const __attribute__((address_space(1))) unsigned int*)g,
        (__attribute__((address_space(3))) unsigned int*)l, 16, 0, 0);
}

// ---------------------------------------------------------------------------
// prep v3 (r15 verbatim, measured 17.0 us):
//   blocks [0,488):  FIR. Block = 2 tasks; task = (b, lg): 4 rows x 128
//     d-quads. 15 float4 sliding window, 8 ch x 4 rows, ushort4 stores.
//   blocks [488,2536): Ws f32 -> bf16 (one float4 per thread).
// ---------------------------------------------------------------------------
__global__ __launch_bounds__(256) void prep(const float* __restrict__ inp,
                                            const float* __restrict__ Ws,
                                            const float* __restrict__ Wt,
                                            unsigned short* __restrict__ tmp,
                                            unsigned short* __restrict__ wsb) {
    int bid = blockIdx.x;
    int tid = threadIdx.x;

    if (bid >= NFIRB) {                     // ---- Ws convert path ----
        int g = (bid - NFIRB) * 256 + tid;  // 524288 float4s
        float4 v = ((const float4*)Ws)[g];
        ushort4 o;
        o.x = f2bf(v.x); o.y = f2bf(v.y); o.z = f2bf(v.z); o.w = f2bf(v.w);
        ((ushort4*)wsb)[g] = o;
        return;
    }

    // ---- FIR path ----
    __shared__ float wt_s[C_][P_];
    if (tid < C_ * P_) wt_s[tid / P_][tid % P_] = Wt[tid];
    __syncthreads();

    int task = bid * 2 + (tid >> 7);    // 0..975 = b*61 + lg
    int dq   = tid & 127;               // d-quad
    int b  = task / 61, lg = task % 61;
    int l0 = lg * 4;
    int d0 = dq * 4;

    float4 rv[15];
    const float* ibase = inp + ((size_t)b * L_ + l0) * D_ + d0;
#pragma unroll
    for (int j = 0; j < 15; ++j)
        rv[j] = *(const float4*)(ibase + (size_t)j * D_);

#pragma unroll
    for (int c = 0; c < C_; ++c) {
        float w[P_];
#pragma unroll
        for (int p = 0; p < P_; ++p) w[p] = wt_s[c][p];
        unsigned short* ob = tmp + (((size_t)(c * B_ + b)) * LOUT + l0) * D_ + d0;
#pragma unroll
        for (int j = 0; j < 4; ++j) {
            float sx = 0.f, sy = 0.f, sz = 0.f, sw = 0.f;
#pragma unroll
            for (int p = 0; p < P_; ++p) {
                sx += w[p] * rv[j + p].x;
                sy += w[p] * rv[j + p].y;
                sz += w[p] * rv[j + p].z;
                sw += w[p] * rv[j + p].w;
            }
            ushort4 ov;
            ov.x = f2bf(sx); ov.y = f2bf(sy);
            ov.z = f2bf(sz); ov.w = f2bf(sw);
            *(ushort4*)(ob + (size_t)j * D_) = ov;
        }
    }
}

// ---------------------------------------------------------------------------
// gemm (round 18): 256x256 tile — staged DMA bytes 190 -> 128 MB (the
//   measured binder: 7.8 TB/s effective global_load_lds throughput).
//   1024 thr = 16 waves (4m x 4n), wave tile 64x64 (identical per-wave
//   geometry to the verified r12 step), acc[4][4] (~120 VGPR -> 16 waves/CU
//   = 4/SIMD). LDS 3 x 32 KB = 96 KB, 1 block/CU, grid 256 = one round.
//   Sync: r12's provable 3-buffer one-barrier counted-vmcnt scheme:
//     MFMA(t) -> lgkmcnt(0) -> STAGE(t+2) -> vmcnt(2) (0 at tail) -> barrier.
//   Staging: global_load_lds x16, linear dest + source swizzle cc^(row&3),
//   reads apply same XOR. bid: c = bid&7 -> channel per XCD.
// ---------------------------------------------------------------------------
__global__ __launch_bounds__(1024, 4) void gemm_k(const unsigned short* __restrict__ tmp,
                                                  const unsigned short* __restrict__ wsb,
                                                  const float* __restrict__ bs,
                                                  const float* __restrict__ Wt,
                                                  const float* __restrict__ bt,
                                                  float* __restrict__ out) {
    __shared__ unsigned short As[3][BM * BK];   // 3 x 16 KB
    __shared__ unsigned short Bs[3][BN * BK];   // 3 x 16 KB

    int bid = blockIdx.x;
    int c  = bid & 7;
    int nt = (bid >> 3) & 1;
    int mt = bid >> 4;                 // 0..15
    int row0 = mt * BM;
    int o0   = nt * BN;
    int tid = threadIdx.x, lane = tid & 63, wid = tid >> 6;
    int wm = wid >> 2, wn = wid & 3;   // 4 x 4 wave grid; wave tile 64x64

    const unsigned short* Ab = tmp + (size_t)c * GM * D_;
    const unsigned short* Bb = wsb + ((size_t)c * O_ + o0) * D_;

    f32x4 acc[4][4];
#pragma unroll
    for (int m = 0; m < 4; ++m)
#pragma unroll
        for (int n = 0; n < 4; ++n)
            acc[m][n] = (f32x4){0.f, 0.f, 0.f, 0.f};

    // per stage: A 1024 chunks + B 1024 chunks; 1+1 insts per thread
#define STAGE(bi, kb)                                                         \
    {                                                                         \
        int row = tid >> 2, cc = tid & 3;                                     \
        int sc = cc ^ (row & 3);                                              \
        int ar = row0 + row; if (ar > GM - 1) ar = GM - 1;                    \
        async_copy16(Ab + (size_t)ar * D_ + (kb) + sc * 8,                    \
                     (unsigned short*)As[bi] + tid * 8);                      \
        async_copy16(Bb + (size_t)row * D_ + (kb) + sc * 8,                   \
                     (unsigned short*)Bs[bi] + tid * 8);                      \
    }

    // one K=32 slice: 4x4 MFMA per wave (r12-verified frag reads)
#define MFMA_STEP(bi)                                                         \
    {                                                                         \
        bf16x8 af[4], bq[4];                                                  \
        _Pragma("unroll")                                                     \
        for (int m = 0; m < 4; ++m) {                                         \
            int r = wm * 64 + m * 16 + (lane & 15);                           \
            af[m] = *(const bf16x8*)&As[bi][r * BK +                          \
                    (((lane >> 4) ^ (r & 3)) << 3)];                          \
        }                                                                     \
        _Pragma("unroll")                                                     \
        for (int n = 0; n < 4; ++n) {                                         \
            int o = wn * 64 + n * 16 + (lane & 15);                           \
            bq[n] = *(const bf16x8*)&Bs[bi][o * BK +                          \
                    (((lane >> 4) ^ (o & 3)) << 3)];                          \
        }                                                                     \
        _Pragma("unroll")                                                     \
        for (int m = 0; m < 4; ++m)                                           \
            _Pragma("unroll")                                                 \
            for (int n = 0; n < 4; ++n)                                       \
                acc[m][n] = __builtin_amdgcn_mfma_f32_16x16x32_bf16(          \
                    af[m], bq[n], acc[m][n], 0, 0, 0);                        \
    }

    // ---- prologue: stage 0,1; drain both (provable); barrier ----
    STAGE(0, 0)
    STAGE(1, BK)
    asm volatile("s_waitcnt vmcnt(0)" ::: "memory");
    __builtin_amdgcn_sched_barrier(0);
    asm volatile("s_barrier" ::: "memory");

    // ---- K-loop: 16 steps, 3-buffer, ONE barrier per step ----
#pragma unroll
    for (int t = 0; t < NSTEP; ++t) {
        MFMA_STEP(t % 3)
        if (t == NSTEP - 1) break;
        asm volatile("s_waitcnt lgkmcnt(0)" ::: "memory");
        __builtin_amdgcn_sched_barrier(0);
        if (t + 2 < NSTEP) STAGE((t + 2) % 3, (t + 2) * BK)
        if (t < NSTEP - 2)
            asm volatile("s_waitcnt vmcnt(2)" ::: "memory");  // certify t+1
        else
            asm volatile("s_waitcnt vmcnt(0)" ::: "memory");  // tail
        __builtin_amdgcn_sched_barrier(0);
        asm volatile("s_barrier" ::: "memory");   // step separator
    }

    // ---- bias + store ----
    float S = 0.f;
#pragma unroll
    for (int p = 0; p < P_; ++p) S += Wt[c * P_ + p];
    float btc = bt[c];

#pragma unroll
    for (int m = 0; m < 4; ++m) {
        int rb = row0 + wm * 64 + m * 16 + ((lane >> 4) << 2);
#pragma unroll
        for (int n = 0; n < 4; ++n) {
            int col = o0 + wn * 64 + n * 16 + (lane & 15);
            float add = bs[c * O_ + col] * S + btc;
#pragma unroll
            for (int i = 0; i < 4; ++i) {
                int r = rb + i;
                if (r < GM)
                    out[((size_t)r * C_ + c) * O_ + col] = acc[m][n][i] + add;
            }
        }
    }
#undef STAGE
#undef MFMA_STEP
}

// ---------------------------------------------------------------------------
// Fallback (ws too small): slow but correct, no workspace.
// ---------------------------------------------------------------------------
__global__ __launch_bounds__(256) void naive_k(const float* __restrict__ inp,
                                               const float* __restrict__ Ws,
                                               const float* __restrict__ bs,
                                               const float* __restrict__ Wt,
                                               const float* __restrict__ bt,
                                               float* __restrict__ out) {
    __shared__ float tmp[D_];
    int bid = blockIdx.x;
    int c = bid & 7; int r = bid >> 3;
    int l = r % LOUT; int b = r / LOUT;
    int tid = threadIdx.x;

    for (int d = tid; d < D_; d += 256) {
        float s = 0.f;
        for (int p = 0; p < P_; ++p)
            s += Wt[c * P_ + p] * inp[((size_t)b * L_ + l + p) * D_ + d];
        tmp[d] = s;
    }
    __syncthreads();
    float S = 0.f;
    for (int p = 0; p < P_; ++p) S += Wt[c * P_ + p];
    for (int o = tid; o < O_; o += 256) {
        const float* wrow = Ws + ((size_t)c * O_ + o) * D_;
        float s = 0.f;
        for (int d = 0; d < D_; ++d) s += wrow[d] * tmp[d];
        out[(((size_t)b * LOUT + l) * C_ + c) * O_ + o] =
            s + bs[c * O_ + o] * S + bt[c];
    }
}

extern "C" void kernel_launch(void* const* d_in, const int* in_sizes, int n_in,
                              void* d_out, int out_size, void* d_ws, size_t ws_size,
                              hipStream_t stream) {
    const float* inp = (const float*)d_in[0];
    const float* Ws  = (const float*)d_in[1];
    const float* bs  = (const float*)d_in[2];
    const float* Wt  = (const float*)d_in[3];
    const float* bt  = (const float*)d_in[4];
    float* out = (float*)d_out;

    const size_t TMPB = (size_t)C_ * GM * D_ * 2;   // 31,981,568
    const size_t WSBB = (size_t)C_ * O_ * D_ * 2;   //  4,194,304

    if (ws_size >= TMPB + WSBB) {
        unsigned short* tmpb = (unsigned short*)d_ws;
        unsigned short* wsb  = (unsigned short*)((char*)d_ws + TMPB);
        prep<<<NFIRB + 2048, 256, 0, stream>>>(inp, Ws, Wt, tmpb, wsb);
        gemm_k<<<NMT * NNT * C_, 1024, 0, stream>>>(tmpb, wsb, bs, Wt, bt, out);
    } else {
        naive_k<<<B_ * LOUT * C_, 256, 0, stream>>>(inp, Ws, bs, Wt, bt, out);
    }
}